// Round 3
// baseline (408.130 us; speedup 1.0000x reference)
//
#include <hip/hip_runtime.h>
#include <math.h>

#define B_SZ 1024
#define K_SZ 24
#define H_SZ 64
#define NVIS 256
#define PLANES 4   // output planes per block; 24/PLANES groups per batch

// ---------------------------------------------------------------------------
// The conv input is a sum of per-(b,c) delta functions, so the op is a scatter
// of 5x5 weight patches into [B,24,64,64]. Floor = 402.6 MB output write
// (~65 us at 6.25 TB/s measured fill BW). Everything else must hide under it.
//
// gs_prep: one thread per (b,k): rounding quirks + kill list. Kill test is a
// packed-code match (vb*24+vk == bk) against an LDS-staged table.
//
// gs_main: one block per (b, group-of-4-o-planes). Spike positions and the
// LDS scatter ADDRESSES are plane-independent -> computed once per block.
// Per plane only 12 coalesced weight loads (issued up front, latency hidden
// under earlier planes' stores), <=3 LDS atomics/thread, then a fused
// store+rezero pass (each thread owns its 16 floats exclusively).
// ---------------------------------------------------------------------------

__global__ __launch_bounds__(256) void gs_prep(
    const float2* __restrict__ x,         // [B*K] (x,y)
    const int*    __restrict__ vis_b,     // [256]
    const int*    __restrict__ vis_k,     // [256]
    int*          __restrict__ spike_tab) // [B*K] packed y*64+x or -1
{
    __shared__ int kill[NVIS];
    const int tid = threadIdx.x;
    const int bk  = blockIdx.x * 256 + tid;       // exactly B*K threads
    kill[tid] = vis_b[tid] * K_SZ + vis_k[tid];   // packed kill code
    const float2 c = x[bk];
    // match jnp.round((v+1.0)*0.5*(H-1)): same op order, rintf = half-to-even
    const int cx = (int)rintf((c.x + 1.0f) * 0.5f * 63.0f);
    const int cy = (int)rintf((c.y + 1.0f) * 0.5f * 63.0f);
    // in-range AND torch quirk (x-coord != 0) => cx in [1,64)
    const bool ok = (cx >= 1) & (cx < H_SZ) & (cy >= 0) & (cy < H_SZ);
    int s = ok ? (cy * H_SZ + cx) : -1;
    __syncthreads();
#pragma unroll 16
    for (int i = 0; i < NVIS; ++i)        // broadcast LDS reads, no conflicts
        if (kill[i] == bk) s = -1;
    spike_tab[bk] = s;
}

__global__ __launch_bounds__(256) void gs_main(
    const int*   __restrict__ spike_tab, // [B*K]
    const float* __restrict__ w,         // [K,K,5,5] OIHW
    float*       __restrict__ out)       // [B,K,64,64]
{
    __shared__ float tile[H_SZ * H_SZ];  // 16 KB -> 8 blocks/CU
    const int bid = blockIdx.x;          // [0, 1024*6)
    const int b   = bid / (K_SZ / PLANES);
    const int o0  = (bid - b * (K_SZ / PLANES)) * PLANES;
    const int tid = threadIdx.x;

    // ---- per-block (plane-independent) tap setup: <=3 taps/thread ----
    const int* sp = spike_tab + b * K_SZ;
    int addr[3];                         // LDS float index or -1
    int tt[3];                           // tap index for weight lookup
#pragma unroll
    for (int it = 0; it < 3; ++it) {
        const int t = tid + it * 256;
        addr[it] = -1;
        tt[it]   = 0;
        if (t < K_SZ * 25) {
            tt[it] = t;
            const int c  = t / 25;
            const int p  = t - c * 25;
            const int s  = sp[c];        // 1-2 cache lines, lane-broadcast
            if (s >= 0) {
                const int y  = s >> 6;
                const int xx = s & 63;
                const int di = p / 5;
                const int dj = p - di * 5;
                const int i  = y + 2 - di;
                const int j  = xx + 2 - dj;
                if (((unsigned)i < H_SZ) & ((unsigned)j < H_SZ))
                    addr[it] = i * H_SZ + j;
            }
        }
    }

    // ---- issue ALL weight loads up front (coalesced; latency overlaps) ----
    float wv[PLANES][3];
#pragma unroll
    for (int p = 0; p < PLANES; ++p) {
        const float* wo = w + (o0 + p) * (K_SZ * 25);
#pragma unroll
        for (int it = 0; it < 3; ++it) wv[p][it] = wo[tt[it]];
    }

    // ---- zero tile once ----
    float4* t4 = (float4*)tile;
    const float4 z = make_float4(0.f, 0.f, 0.f, 0.f);
#pragma unroll
    for (int r = 0; r < 4; ++r) t4[r * 256 + tid] = z;
    __syncthreads();

    // ---- per plane: scatter -> barrier -> store+rezero -> barrier ----
#pragma unroll
    for (int p = 0; p < PLANES; ++p) {
#pragma unroll
        for (int it = 0; it < 3; ++it)
            if (addr[it] >= 0) atomicAdd(&tile[addr[it]], wv[p][it]);
        __syncthreads();

        float4* o4 = (float4*)(out + ((size_t)(b * K_SZ + o0 + p) << 12));
#pragma unroll
        for (int r = 0; r < 4; ++r) {
            const int idx = r * 256 + tid;
            const float4 v = t4[idx];
            o4[idx] = v;
            if (p < PLANES - 1) t4[idx] = z;   // rezero own slots (exclusive)
        }
        if (p < PLANES - 1) __syncthreads();
    }
}

extern "C" void kernel_launch(void* const* d_in, const int* in_sizes, int n_in,
                              void* d_out, int out_size, void* d_ws, size_t ws_size,
                              hipStream_t stream) {
    const float2* x     = (const float2*)d_in[0];
    const float*  w     = (const float*)d_in[1];
    const int*    vis_b = (const int*)d_in[2];
    const int*    vis_k = (const int*)d_in[3];
    float*        out   = (float*)d_out;
    int*          spike_tab = (int*)d_ws;   // 24576 * 4 B = 96 KB scratch

    gs_prep<<<(B_SZ * K_SZ) / 256, 256, 0, stream>>>(x, vis_b, vis_k, spike_tab);
    gs_main<<<B_SZ * (K_SZ / PLANES), 256, 0, stream>>>(spike_tab, w, out);
}

// Round 5
// 390.332 us; speedup vs baseline: 1.0456x; 1.0456x over previous
//
#include <hip/hip_runtime.h>
#include <math.h>

#define B_SZ 1024
#define K_SZ 24
#define H_SZ 64
#define NVIS 256

typedef float vfloat4 __attribute__((ext_vector_type(4)));  // native vec type
                                                            // (HIP float4 is a
                                                            // class; builtin
                                                            // rejects it)

// ---------------------------------------------------------------------------
// The conv input is a sum of per-(b,c) delta functions, so the op is a scatter
// of 5x5 weight patches into [B,24,64,64]. Floor = 402.6 MB output write
// (~64.5 us at the 6.25 TB/s the harness's own fill kernels achieve).
//
// R3 lesson: plane-grouping (PLANES=4) regressed — per-block barrier
// serialization costs more than prolog amortization saves. So: one plane per
// block, 24576 independent blocks, exactly 2 barriers each.
//
// gs_prep: one thread per (b,k). Kill test is O(1): each thread scatters its
// vis entry's packed code into an LDS flag array covering the block's
// contiguous bk range (vis code = vb*24+vk == bk <=> flag[bk-base]).
//
// gs_main: one block per (b,o) plane. Prolog loads (spike slice + weight
// slice) issue first so latency overlaps the LDS zero-fill; <=600 LDS
// atomics; then a coalesced float4 store pass using NON-TEMPORAL stores so
// the 402 MB output stream does not evict the L2-resident spike/weight
// working set that every block re-reads.
// ---------------------------------------------------------------------------

__global__ __launch_bounds__(256) void gs_prep(
    const float2* __restrict__ x,         // [B*K] (x,y)
    const int*    __restrict__ vis_b,     // [256]
    const int*    __restrict__ vis_k,     // [256]
    int*          __restrict__ spike_tab) // [B*K] packed y*64+x or -1
{
    __shared__ unsigned char killf[256];
    const int tid  = threadIdx.x;
    const int base = blockIdx.x * 256;
    const int bk   = base + tid;               // exactly B*K threads
    killf[tid] = 0;

    // spike position: match jnp.round((v+1.0)*0.5*(H-1)); rintf = half-to-even
    const float2 c = x[bk];
    const int cx = (int)rintf((c.x + 1.0f) * 0.5f * 63.0f);
    const int cy = (int)rintf((c.y + 1.0f) * 0.5f * 63.0f);
    // in-range AND torch quirk (x-coord != 0) => cx in [1,64)
    const bool ok = (cx >= 1) & (cx < H_SZ) & (cy >= 0) & (cy < H_SZ);
    int s = ok ? (cy * H_SZ + cx) : -1;

    // kill scatter: code == bk <=> this block's flag slot (racy same-value ok)
    const int code = vis_b[tid] * K_SZ + vis_k[tid];
    __syncthreads();                            // killf init complete
    const unsigned local = (unsigned)(code - base);
    if (local < 256u) killf[local] = 1;
    __syncthreads();
    if (killf[tid]) s = -1;
    spike_tab[bk] = s;
}

__global__ __launch_bounds__(256) void gs_main(
    const int*   __restrict__ spike_tab, // [B*K]
    const float* __restrict__ w,         // [K,K,5,5] OIHW, 600 floats per o
    float*       __restrict__ out)       // [B,K,64,64]
{
    __shared__ float tile[H_SZ * H_SZ];  // 16 KB; wave-limit -> 8 blocks/CU
    const int bid = blockIdx.x;
    const int b   = bid / K_SZ;
    const int o   = bid - b * K_SZ;
    const int tid = threadIdx.x;

    // ---- issue scatter-phase global loads first (latency overlaps zeroing)
    const int*   sp = spike_tab + b * K_SZ;
    const float* wo = w + o * (K_SZ * 25);
    int sv[3]; float wv[3]; int pp[3];
#pragma unroll
    for (int it = 0; it < 3; ++it) {
        const int t = tid + it * 256;
        sv[it] = -1;
        if (t < K_SZ * 25) {
            const int c = t / 25;
            pp[it] = t - c * 25;
            sv[it] = sp[c];        // 1-2 cache lines, lane-broadcast, L2-hit
            wv[it] = wo[t];        // fully coalesced, L2-hit
        }
    }

    // ---- zero the accumulation tile with b128 stores
    vfloat4* t4 = (vfloat4*)tile;
    const vfloat4 z = {0.f, 0.f, 0.f, 0.f};
#pragma unroll
    for (int r = 0; r < 4; ++r) t4[r * 256 + tid] = z;
    __syncthreads();

    // ---- scatter <=600 taps: out[i,j] += w[o,c,di,dj], i=y+2-di, j=x+2-dj
#pragma unroll
    for (int it = 0; it < 3; ++it) {
        const int s = sv[it];
        if (s >= 0) {
            const int y  = s >> 6;
            const int xx = s & 63;
            const int di = pp[it] / 5;
            const int dj = pp[it] - di * 5;
            const int i  = y + 2 - di;
            const int j  = xx + 2 - dj;
            if (((unsigned)i < H_SZ) & ((unsigned)j < H_SZ))
                atomicAdd(&tile[i * H_SZ + j], wv[it]);
        }
    }
    __syncthreads();

    // ---- stream the 16 KB plane out: coalesced, NON-TEMPORAL float4
    vfloat4* o4 = (vfloat4*)(out + ((size_t)bid << 12));
#pragma unroll
    for (int r = 0; r < 4; ++r) {
        const int idx = r * 256 + tid;
        __builtin_nontemporal_store(t4[idx], &o4[idx]);
    }
}

extern "C" void kernel_launch(void* const* d_in, const int* in_sizes, int n_in,
                              void* d_out, int out_size, void* d_ws, size_t ws_size,
                              hipStream_t stream) {
    const float2* x     = (const float2*)d_in[0];
    const float*  w     = (const float*)d_in[1];
    const int*    vis_b = (const int*)d_in[2];
    const int*    vis_k = (const int*)d_in[3];
    float*        out   = (float*)d_out;
    int*          spike_tab = (int*)d_ws;   // 24576 * 4 B = 96 KB scratch

    gs_prep<<<(B_SZ * K_SZ) / 256, 256, 0, stream>>>(x, vis_b, vis_k, spike_tab);
    gs_main<<<B_SZ * K_SZ, 256, 0, stream>>>(spike_tab, w, out);
}